// Round 11
// baseline (152.703 us; speedup 1.0000x reference)
//
#include <hip/hip_runtime.h>
#include <hip/hip_bf16.h>
#include <math.h>

typedef __attribute__((ext_vector_type(8))) short bf16x8;
typedef __attribute__((ext_vector_type(4))) float f32x4;
typedef unsigned long long u64;

#define NSAMP  128000
#define TFR    501
#define NFR    32064       // 64*501 frames per signal
#define FPOW   257
#define NF     257
#define B_SZ   64
#define CHUNKT 32
#define NCH    16
#define EPS_F  1.1920928955078125e-07f

#define BCOLS  128         // basis cols per block (of 512)
#define ASEGB  32768       // 16384 bf16 samples = 63 frames + halo, exactly
#define LDS_TOTAL (ASEGB + BCOLS * 1024)   // 163840 B = full 160 KiB
#define CFR    63          // frames per chunk
#define NCHK   8           // 8*63 = 504 >= 501

// ---- basis, layout [col 0..511][k 0..511] bf16 --------------------------
// col = (bin>>4)*32 + isIm*16 + (bin&15); col 16 (dead im of DC) = Nyquist.
__global__ __launch_bounds__(256)
void build_basis(unsigned short* __restrict__ Bt) {
    int col = blockIdx.x;
    int g = col >> 5, o = col & 15;
    int isIm = (col >> 4) & 1;
    int bin = g * 16 + o;
    for (int k = threadIdx.x; k < 512; k += 256) {
        float w = sinf((float)k * (float)(M_PI / 512.0));   // sqrt-hann
        float v;
        if (col == 16) {
            v = w * ((k & 1) ? -1.f : 1.f);
        } else {
            int mm = (bin * k) & 511;
            float th = (float)mm * (float)(2.0 * M_PI / 512.0);
            v = w * (isIm ? -sinf(th) : cosf(th));
        }
        __hip_bfloat16 h = __float2bfloat16(v);
        Bt[(size_t)col * 512 + k] = *reinterpret_cast<unsigned short*>(&h);
    }
}

// ---- MFMA DFT GEMM v11: persistent-B, barrier-free K-loop ---------------
// grid (4 colgroups, 128 sb) = 512 blocks, block 256 (4 waves = 2M x 2N).
// B: this block's 128 cols x K512 resident in LDS for the WHOLE kernel
//    (staged once via global_load_lds, swizzled source). No K-loop staging.
// A: 63-frame raw bf16 window (32KB incl halo), re-staged per chunk with
//    T14 reg-prefetch; 8 chunks cover 501 frames. 2 barriers per chunk.
__global__ __launch_bounds__(256, 1)
void dft_gemm(const float* __restrict__ sig,
              const float* __restrict__ intf,
              const unsigned short* __restrict__ Bt,
              _Float16* __restrict__ powo)
{
    extern __shared__ char smem[];
    char* As = smem;              // 32KB swizzled raw bf16 samples
    char* Bl = smem + ASEGB;      // 128KB basis cols (swizzled)

    const int g = blockIdx.x, sb = blockIdx.y;
    const int tid = threadIdx.x, lane = tid & 63, wid = tid >> 6;
    const int wm = wid >> 1, wn = wid & 1;          // 2M x 2N waves
    const int lq = lane >> 4, ll = lane & 15;
    const float* x = ((sb >> 6) ? sig : intf) + (size_t)(sb & 63) * NSAMP;

    float4 buf[16];
    auto loadA = [&](int c) {      // issue 16 float4 loads into regs
        const int tb = c * (CFR * 256) - 256;
        #pragma unroll
        for (int n = 0; n < 16; ++n) {
            int j = (tid + n * 256) * 4;
            int p0 = tb + j;
            if (p0 >= 0 && p0 + 4 <= NSAMP) {
                buf[n] = *(const float4*)(x + p0);
            } else {
                float f[4];
                #pragma unroll
                for (int e = 0; e < 4; ++e) {
                    int p = p0 + e;
                    if (p < 0) p = -p;
                    if (p >= NSAMP) p = 2 * NSAMP - 2 - p;
                    f[e] = x[p];
                }
                buf[n] = make_float4(f[0], f[1], f[2], f[3]);
            }
        }
    };
    auto writeA = [&]() {          // convert + swizzled ds_write
        #pragma unroll
        for (int n = 0; n < 16; ++n) {
            unsigned short h[4];
            __hip_bfloat16 t0 = __float2bfloat16(buf[n].x); h[0] = *(unsigned short*)&t0;
            __hip_bfloat16 t1 = __float2bfloat16(buf[n].y); h[1] = *(unsigned short*)&t1;
            __hip_bfloat16 t2 = __float2bfloat16(buf[n].z); h[2] = *(unsigned short*)&t2;
            __hip_bfloat16 t3 = __float2bfloat16(buf[n].w); h[3] = *(unsigned short*)&t3;
            u64 pk = (u64)h[0] | ((u64)h[1] << 16) | ((u64)h[2] << 32) | ((u64)h[3] << 48);
            int a = (tid + n * 256) * 8;
            a ^= ((a >> 9) & 7) << 4;
            *(u64*)(As + a) = pk;
        }
    };

    // ---- stage this block's 128 basis cols ONCE (swizzled source) ----
    {
        const char* gb = (const char*)Bt + (size_t)g * BCOLS * 1024;
        #pragma unroll
        for (int i = 0; i < 32; ++i) {
            int col = i * 4 + wid;                       // wave-uniform
            const char* src = gb + (size_t)col * 1024 + ((lane ^ (col & 7)) * 16);
            char* dst = Bl + col * 1024;
            __builtin_amdgcn_global_load_lds(
                (const __attribute__((address_space(1))) void*)src,
                (__attribute__((address_space(3))) void*)dst, 16, 0, 0);
        }
    }
    loadA(0);
    writeA();                                            // waits A regs only
    asm volatile("s_waitcnt vmcnt(0)" ::: "memory");     // B landed
    __syncthreads();

    const size_t rowbase = (size_t)sb * TFR;

    for (int c = 0; c < NCHK; ++c) {
        if (c < NCHK - 1) loadA(c + 1);   // T14: in flight across the K-loop

        f32x4 acc[2][4];
        #pragma unroll
        for (int i = 0; i < 2; ++i)
            #pragma unroll
            for (int j = 0; j < 4; ++j) acc[i][j] = 0;

        // ---- barrier-free K-loop: 16 ksteps x (6 ds_read_b128 -> 8 MFMA) ----
        #pragma unroll
        for (int ks = 0; ks < 16; ++ks) {
            bf16x8 af[2], bfr[4];
            #pragma unroll
            for (int mf = 0; mf < 2; ++mf) {
                int a = (wm * 32 + mf * 16 + ll) * 512 + ks * 64 + lq * 16;
                a ^= ((a >> 9) & 7) << 4;
                a &= (ASEGB - 1);         // row 63 (masked garbage) wraps
                af[mf] = *(const bf16x8*)(As + a);
            }
            #pragma unroll
            for (int nf = 0; nf < 4; ++nf) {
                int bo = (wn * 64 + nf * 16 + ll) * 1024 + ks * 64 + lq * 16;
                bo ^= ((bo >> 10) & 7) << 4;
                bfr[nf] = *(const bf16x8*)(Bl + bo);
            }
            #pragma unroll
            for (int mf = 0; mf < 2; ++mf)
                #pragma unroll
                for (int nf = 0; nf < 4; ++nf)
                    acc[mf][nf] = __builtin_amdgcn_mfma_f32_16x16x32_bf16(
                        af[mf], bfr[nf], acc[mf][nf], 0, 0, 0);
        }

        // ---- epilogue: power = re^2 + im^2, fp16 stores ----
        #pragma unroll
        for (int mf = 0; mf < 2; ++mf) {
            #pragma unroll
            for (int p = 0; p < 2; ++p) {
                f32x4 re = acc[mf][2 * p], im = acc[mf][2 * p + 1];
                int bingrp = g * 4 + wn * 2 + p;       // 16-bin group 0..15
                int bin = bingrp * 16 + ll;
                bool nyq = (bingrp == 0) && (ll == 0);
                #pragma unroll
                for (int j = 0; j < 4; ++j) {
                    int rowloc = wm * 32 + mf * 16 + lq * 4 + j;
                    int rl = c * CFR + rowloc;
                    if (rowloc < CFR && rl < TFR) {
                        float pr = re[j] * re[j];
                        float pi = im[j] * im[j];
                        _Float16* po = powo + (rowbase + rl) * FPOW;
                        po[bin] = (_Float16)(nyq ? pr : (pr + pi));
                        if (nyq) po[256] = (_Float16)pi;
                    }
                }
            }
        }
        __syncthreads();                  // all waves done reading A(c)
        if (c < NCHK - 1) { writeA(); __syncthreads(); }
    }
}

// ---- warm-up: batched loads then fmaf chain (fp16 planes) ---------------
template<int W>
__device__ __forceinline__ float warm_sum(const _Float16* __restrict__ nrow,
                                          int ts, float alpha, float oma) {
    float q[W + 1];
    #pragma unroll
    for (int i = 0; i <= W; ++i) q[i] = (float)nrow[(size_t)(ts + i) * FPOW];
    float v = q[0];
    #pragma unroll
    for (int i = 1; i <= W; ++i) v = fmaf(alpha, v, oma * q[i]);
    return v;
}

// ---- chunked IIR scan + SPP + MSE, fp16 power planes --------------------
__global__ __launch_bounds__(256, 4)
void spp_loss_kernel(const _Float16* __restrict__ noiseP,
                     const _Float16* __restrict__ noisyP,
                     const float* __restrict__ est,
                     float* __restrict__ out,
                     float alpha)
{
    const double XI = 31.622776601683793;
    const float RATIO = (float)(1.0 + XI);
    const float COEF  = (float)(XI / (1.0 + XI));
    const float INVN  = (float)(1.0 / ((double)B_SZ * NF * TFR));

    int tid = blockIdx.x * blockDim.x + threadIdx.x;
    int f   = tid % NF;
    int rem = tid / NF;
    int c   = rem & (NCH - 1);
    int b   = rem >> 4;

    float local = 0.f;
    if (b < B_SZ) {
        const int t0   = c * CHUNKT;
        const int tend = min(TFR, t0 + CHUNKT);
        const _Float16* nrow = noiseP + (size_t)b * TFR * FPOW + f;
        const _Float16* yrow = noisyP + (size_t)b * TFR * FPOW + f;
        const float* erow = est + ((size_t)b * NF + f) * TFR;
        const float oma = 1.f - alpha;

        float v;
        if (t0 == 0)            v = (float)nrow[0];
        else if (t0 == CHUNKT)  v = warm_sum<CHUNKT>(nrow, 0, alpha, oma);
        else                    v = warm_sum<48>(nrow, t0 - 48, alpha, oma);

        {
            float np = (float)yrow[(size_t)t0 * FPOW];
            float e0 = erow[t0];
            float expo = -np / (v + EPS_F) * COEF;
            float spp  = 1.f / fmaf(RATIO, __expf(expo), 1.f);
            float d = e0 - spp;
            local = fmaf(d, d, local);
        }
        #pragma unroll
        for (int h = 0; h < 2; ++h) {
            float qn[16], qy[16], qe[16];
            #pragma unroll
            for (int i = 0; i < 16; ++i) {
                int t = min(t0 + h * 16 + i + 1, TFR - 1);
                qn[i] = (float)nrow[(size_t)t * FPOW];
                qy[i] = (float)yrow[(size_t)t * FPOW];
                qe[i] = erow[t];
            }
            #pragma unroll
            for (int i = 0; i < 16; ++i) {
                int t = t0 + h * 16 + i + 1;
                v = fmaf(alpha, v, oma * qn[i]);
                if (t < tend) {
                    float expo = -qy[i] / (v + EPS_F) * COEF;
                    float spp  = 1.f / fmaf(RATIO, __expf(expo), 1.f);
                    float d = qe[i] - spp;
                    local = fmaf(d, d, local);
                }
            }
        }
    }

    for (int off = 32; off > 0; off >>= 1)
        local += __shfl_down(local, off);
    __shared__ float wsum[4];
    if ((threadIdx.x & 63) == 0) wsum[threadIdx.x >> 6] = local;
    __syncthreads();
    if (threadIdx.x == 0) {
        float ssum = (wsum[0] + wsum[1]) + (wsum[2] + wsum[3]);
        atomicAdd(out, ssum * INVN);
    }
}

extern "C" void kernel_launch(void* const* d_in, const int* in_sizes, int n_in,
                              void* d_out, int out_size, void* d_ws, size_t ws_size,
                              hipStream_t stream) {
    const float* est  = (const float*)d_in[0];   // spp_estimate (B,1,F,T)
    const float* sig  = (const float*)d_in[1];   // input_sig    (B,1,N)
    const float* intf = (const float*)d_in[2];   // interference (B,1,N)

    unsigned short* Bt = (unsigned short*)d_ws;                 // 512 KB basis
    _Float16* powp = (_Float16*)((char*)d_ws + (size_t)512 * 1024);

    hipLaunchKernelGGL(build_basis, dim3(512), dim3(256), 0, stream, Bt);
    hipMemsetAsync(d_out, 0, sizeof(float), stream);

    hipFuncSetAttribute((const void*)dft_gemm,
                        hipFuncAttributeMaxDynamicSharedMemorySize, LDS_TOTAL);
    dim3 gG(4, 128);
    hipLaunchKernelGGL(dft_gemm, gG, dim3(256), LDS_TOTAL, stream,
                       sig, intf, Bt, powp);

    const double alpha_d = exp(-((double)256) / (16000.0 * 0.072));
    const _Float16* noiseP = powp;                          // s=0: interference
    const _Float16* noisyP = powp + (size_t)NFR * FPOW;     // s=1: input_sig
    dim3 gB((B_SZ * NCH * NF + 255) / 256);
    hipLaunchKernelGGL(spp_loss_kernel, gB, dim3(256), 0, stream,
                       noiseP, noisyP, est, (float*)d_out, (float)alpha_d);
}

// Round 12
// 101.556 us; speedup vs baseline: 1.5036x; 1.5036x over previous
//
#include <hip/hip_runtime.h>
#include <hip/hip_bf16.h>
#include <math.h>

typedef __attribute__((ext_vector_type(8))) short bf16x8;
typedef __attribute__((ext_vector_type(4))) float f32x4;
typedef unsigned long long u64;

#define NSAMP  128000
#define TFR    501
#define NFR    32064       // 64*501 frames per signal
#define FPOW   257
#define NF     257
#define B_SZ   64
#define CHUNKT 32
#define NCH    16
#define EPS_F  1.1920928955078125e-07f

#define SEG    16640       // 64*256 + 256 samples per 64-frame chunk
#define SEGB   33280       // SEG * 2 bytes (bf16)
#define BPHB   32768       // one phase: 512 cols x 32 k bf16 = 32 KB
#define LDS_TOTAL (SEGB + BPHB)   // 66048 B -> 2 blocks/CU

// ---- basis, layout [ph(16)][colgrp(32)][lane(64)][8 bf16] ---------------
// col = colgrp*16 + (lane&15); k = ph*32 + (lane>>4)*8 + j.
// col semantic: (bin>>4)*32 + isIm*16 + (bin&15); col 16 = Nyquist basis.
// This makes each MFMA B-fragment read wave-contiguous (lane l -> l*16B):
// structurally bank-conflict-free, and global->LDS staging is identity.
__global__ __launch_bounds__(256)
void build_basis(unsigned short* __restrict__ Bt) {
    int col = blockIdx.x;
    int g = col >> 5, o = col & 15;
    int isIm = (col >> 4) & 1;
    int bin = g * 16 + o;
    for (int k = threadIdx.x; k < 512; k += 256) {
        float w = sinf((float)k * (float)(M_PI / 512.0));   // sqrt-hann
        float v;
        if (col == 16) {
            v = w * ((k & 1) ? -1.f : 1.f);
        } else {
            int mm = (bin * k) & 511;
            float th = (float)mm * (float)(2.0 * M_PI / 512.0);
            v = w * (isIm ? -sinf(th) : cosf(th));
        }
        __hip_bfloat16 h = __float2bfloat16(v);
        int ph = k >> 5, kq = (k >> 3) & 3, j = k & 7;
        size_t idx = (((size_t)ph * 32 + (col >> 4)) * 64
                      + kq * 16 + (col & 15)) * 8 + j;
        Bt[idx] = *reinterpret_cast<unsigned short*>(&h);
    }
}

// ---- MFMA DFT GEMM v12: r10 structure + conflict-free B + fp16 out ------
// grid (8 mchunk, 64 b, 2 s) = 1024 blocks, block 256 (4 waves over N).
// Block tile 64 rows x 512 cols, 16 phases of K=32, single 32KB B buffer.
__global__ __launch_bounds__(256, 2)
void dft_gemm(const float* __restrict__ sig,
              const float* __restrict__ intf,
              const unsigned short* __restrict__ Bt,
              _Float16* __restrict__ powo)
{
    extern __shared__ char smem[];
    char* As = smem;
    char* Bl = smem + SEGB;

    const int mchunk = blockIdx.x, b = blockIdx.y, s = blockIdx.z;
    const int tid = threadIdx.x, lane = tid & 63, wn = tid >> 6;  // 4 waves
    const int lq = lane >> 4, ll = lane & 15;
    const float* x = (s == 0 ? intf : sig) + (size_t)b * NSAMP;
    const int tbase = mchunk * 16384 - 256;

    // stage one 32KB phase tile of B; identity copy (layouts match)
    auto stageB = [&](int ph) {
        const char* gb = (const char*)Bt + (size_t)ph * BPHB;
        #pragma unroll
        for (int i = 0; i < 8; ++i) {
            int o = i * 4096 + tid * 16;
            __builtin_amdgcn_global_load_lds(
                (const __attribute__((address_space(1))) void*)(gb + o),
                (__attribute__((address_space(3))) void*)(Bl + o), 16, 0, 0);
        }
    };

    stageB(0);

    // ---- A staging: contiguous segment, float4, bf16, addr-XOR swizzle ----
    {
        const int jlo = (tbase < 0) ? -tbase : 0;
        const int jhi = (tbase + SEG > NSAMP) ? (NSAMP - tbase) : SEG;
        for (int i = tid; i < SEG / 4; i += 256) {
            int j = i * 4;
            float f0, f1, f2, f3;
            if (j >= jlo && j + 4 <= jhi) {
                float4 v = *(const float4*)(x + tbase + j);
                f0 = v.x; f1 = v.y; f2 = v.z; f3 = v.w;
            } else {
                int p0 = tbase + j;
                int pp[4];
                #pragma unroll
                for (int e = 0; e < 4; ++e) {
                    int p = p0 + e;
                    if (p < 0) p = -p;
                    if (p >= NSAMP) p = 2 * NSAMP - 2 - p;
                    pp[e] = p;
                }
                f0 = x[pp[0]]; f1 = x[pp[1]]; f2 = x[pp[2]]; f3 = x[pp[3]];
            }
            unsigned short h[4];
            __hip_bfloat16 t0 = __float2bfloat16(f0); h[0] = *(unsigned short*)&t0;
            __hip_bfloat16 t1 = __float2bfloat16(f1); h[1] = *(unsigned short*)&t1;
            __hip_bfloat16 t2 = __float2bfloat16(f2); h[2] = *(unsigned short*)&t2;
            __hip_bfloat16 t3 = __float2bfloat16(f3); h[3] = *(unsigned short*)&t3;
            u64 pk = (u64)h[0] | ((u64)h[1] << 16) |
                     ((u64)h[2] << 32) | ((u64)h[3] << 48);
            int a = i * 8;
            a ^= ((a >> 9) & 7) << 4;
            *(u64*)(As + a) = pk;
        }
    }
    asm volatile("s_waitcnt vmcnt(0)" ::: "memory");
    __syncthreads();   // A ready + B tile 0 landed

    f32x4 acc[4][8];
    #pragma unroll
    for (int i = 0; i < 4; ++i)
        #pragma unroll
        for (int j = 0; j < 8; ++j) acc[i][j] = 0;

    for (int ph = 0; ph < 16; ++ph) {
        bf16x8 af[4], bfr[8];
        // ---- 4 A-frag reads (XOR-swizzled, 2-way max) ----
        #pragma unroll
        for (int mf = 0; mf < 4; ++mf) {
            int a = (mf * 16 + ll) * 512 + ph * 64 + lq * 16;
            a ^= ((a >> 9) & 7) << 4;
            af[mf] = *(const bf16x8*)(As + a);
        }
        // ---- 8 B-frag reads, each wave-contiguous 1KB (conflict-free) ----
        #pragma unroll
        for (int nf = 0; nf < 8; ++nf) {
            int bo = ((wn * 8 + nf) * 64 + lane) * 16;
            bfr[nf] = *(const bf16x8*)(Bl + bo);
        }
        __syncthreads();                   // everyone's B reads done; buf free
        if (ph < 15) stageB(ph + 1);       // refill; hides under MFMA cluster
        __builtin_amdgcn_s_setprio(1);
        #pragma unroll
        for (int mf = 0; mf < 4; ++mf)
            #pragma unroll
            for (int nf = 0; nf < 8; ++nf)
                acc[mf][nf] = __builtin_amdgcn_mfma_f32_16x16x32_bf16(
                    af[mf], bfr[nf], acc[mf][nf], 0, 0, 0);
        __builtin_amdgcn_s_setprio(0);
        __syncthreads();                   // vmcnt(0): tile ph+1 landed
    }

    // ---- epilogue: power = re^2 + im^2, fp16 stores ----
    const size_t rowbase = ((size_t)(s * 64 + b)) * TFR;
    #pragma unroll
    for (int mf = 0; mf < 4; ++mf) {
        #pragma unroll
        for (int p = 0; p < 4; ++p) {
            f32x4 re = acc[mf][2 * p], im = acc[mf][2 * p + 1];
            int gbin = wn * 4 + p;
            int bin = gbin * 16 + ll;
            bool nyq = (gbin == 0) && (ll == 0);
            #pragma unroll
            for (int j = 0; j < 4; ++j) {
                int rl = mchunk * 64 + mf * 16 + lq * 4 + j;
                if (rl < TFR) {
                    float pr = re[j] * re[j];
                    float pi = im[j] * im[j];
                    _Float16* po = powo + (rowbase + rl) * FPOW;
                    po[bin] = (_Float16)(nyq ? pr : (pr + pi));
                    if (nyq) po[256] = (_Float16)pi;
                }
            }
        }
    }
}

// ---- warm-up: batched loads then fmaf chain (fp16 planes) ---------------
template<int W>
__device__ __forceinline__ float warm_sum(const _Float16* __restrict__ nrow,
                                          int ts, float alpha, float oma) {
    float q[W + 1];
    #pragma unroll
    for (int i = 0; i <= W; ++i) q[i] = (float)nrow[(size_t)(ts + i) * FPOW];
    float v = q[0];
    #pragma unroll
    for (int i = 1; i <= W; ++i) v = fmaf(alpha, v, oma * q[i]);
    return v;
}

// ---- chunked IIR scan + SPP + MSE, fp16 power planes --------------------
__global__ __launch_bounds__(256, 4)
void spp_loss_kernel(const _Float16* __restrict__ noiseP,
                     const _Float16* __restrict__ noisyP,
                     const float* __restrict__ est,
                     float* __restrict__ out,
                     float alpha)
{
    const double XI = 31.622776601683793;
    const float RATIO = (float)(1.0 + XI);
    const float COEF  = (float)(XI / (1.0 + XI));
    const float INVN  = (float)(1.0 / ((double)B_SZ * NF * TFR));

    int tid = blockIdx.x * blockDim.x + threadIdx.x;
    int f   = tid % NF;
    int rem = tid / NF;
    int c   = rem & (NCH - 1);
    int b   = rem >> 4;

    float local = 0.f;
    if (b < B_SZ) {
        const int t0   = c * CHUNKT;
        const int tend = min(TFR, t0 + CHUNKT);
        const _Float16* nrow = noiseP + (size_t)b * TFR * FPOW + f;
        const _Float16* yrow = noisyP + (size_t)b * TFR * FPOW + f;
        const float* erow = est + ((size_t)b * NF + f) * TFR;
        const float oma = 1.f - alpha;

        float v;
        if (t0 == 0)            v = (float)nrow[0];
        else if (t0 == CHUNKT)  v = warm_sum<CHUNKT>(nrow, 0, alpha, oma);
        else                    v = warm_sum<48>(nrow, t0 - 48, alpha, oma);

        {
            float np = (float)yrow[(size_t)t0 * FPOW];
            float e0 = erow[t0];
            float expo = -np / (v + EPS_F) * COEF;
            float spp  = 1.f / fmaf(RATIO, __expf(expo), 1.f);
            float d = e0 - spp;
            local = fmaf(d, d, local);
        }
        #pragma unroll
        for (int h = 0; h < 2; ++h) {
            float qn[16], qy[16], qe[16];
            #pragma unroll
            for (int i = 0; i < 16; ++i) {
                int t = min(t0 + h * 16 + i + 1, TFR - 1);
                qn[i] = (float)nrow[(size_t)t * FPOW];
                qy[i] = (float)yrow[(size_t)t * FPOW];
                qe[i] = erow[t];
            }
            #pragma unroll
            for (int i = 0; i < 16; ++i) {
                int t = t0 + h * 16 + i + 1;
                v = fmaf(alpha, v, oma * qn[i]);
                if (t < tend) {
                    float expo = -qy[i] / (v + EPS_F) * COEF;
                    float spp  = 1.f / fmaf(RATIO, __expf(expo), 1.f);
                    float d = qe[i] - spp;
                    local = fmaf(d, d, local);
                }
            }
        }
    }

    for (int off = 32; off > 0; off >>= 1)
        local += __shfl_down(local, off);
    __shared__ float wsum[4];
    if ((threadIdx.x & 63) == 0) wsum[threadIdx.x >> 6] = local;
    __syncthreads();
    if (threadIdx.x == 0) {
        float ssum = (wsum[0] + wsum[1]) + (wsum[2] + wsum[3]);
        atomicAdd(out, ssum * INVN);
    }
}

extern "C" void kernel_launch(void* const* d_in, const int* in_sizes, int n_in,
                              void* d_out, int out_size, void* d_ws, size_t ws_size,
                              hipStream_t stream) {
    const float* est  = (const float*)d_in[0];   // spp_estimate (B,1,F,T)
    const float* sig  = (const float*)d_in[1];   // input_sig    (B,1,N)
    const float* intf = (const float*)d_in[2];   // interference (B,1,N)

    unsigned short* Bt = (unsigned short*)d_ws;                 // 512 KB basis
    _Float16* powp = (_Float16*)((char*)d_ws + (size_t)512 * 1024);

    hipLaunchKernelGGL(build_basis, dim3(512), dim3(256), 0, stream, Bt);
    hipMemsetAsync(d_out, 0, sizeof(float), stream);

    hipFuncSetAttribute((const void*)dft_gemm,
                        hipFuncAttributeMaxDynamicSharedMemorySize, LDS_TOTAL);
    dim3 gG(8, 64, 2);
    hipLaunchKernelGGL(dft_gemm, gG, dim3(256), LDS_TOTAL, stream,
                       sig, intf, Bt, powp);

    const double alpha_d = exp(-((double)256) / (16000.0 * 0.072));
    const _Float16* noiseP = powp;                          // s=0: interference
    const _Float16* noisyP = powp + (size_t)NFR * FPOW;     // s=1: input_sig
    dim3 gB((B_SZ * NCH * NF + 255) / 256);
    hipLaunchKernelGGL(spp_loss_kernel, gB, dim3(256), 0, stream,
                       noiseP, noisyP, est, (float*)d_out, (float)alpha_d);
}

// Round 13
// 97.957 us; speedup vs baseline: 1.5589x; 1.0367x over previous
//
#include <hip/hip_runtime.h>
#include <hip/hip_bf16.h>
#include <math.h>

typedef __attribute__((ext_vector_type(8))) short bf16x8;
typedef __attribute__((ext_vector_type(4))) float f32x4;
typedef unsigned long long u64;

#define NSAMP  128000
#define TFR    501
#define NFR    32064       // 64*501 frames per signal
#define FPOW   257
#define NF     257
#define B_SZ   64
#define CHUNKT 32
#define NCH    16
#define EPS_F  1.1920928955078125e-07f

#define SEG    16640       // 64*256 + 256 samples per 64-frame chunk
#define SEGB   33280       // SEG * 2 bytes (bf16)
#define BPHB   32768       // one K=32 phase of basis: 512 cols = 32 KB

// ---- basis, layout [ph(16)][colgrp(32)][lane(64)][8 bf16] ---------------
// col = colgrp*16 + (lane&15); k = ph*32 + (lane>>4)*8 + j.
// col semantic: (bin>>4)*32 + isIm*16 + (bin&15); col 16 = Nyquist basis.
// Wave reading frag (ph,colgrp): lane l -> base + l*16B, fully coalesced.
__global__ __launch_bounds__(256)
void build_basis(unsigned short* __restrict__ Bt) {
    int col = blockIdx.x;
    int g = col >> 5, o = col & 15;
    int isIm = (col >> 4) & 1;
    int bin = g * 16 + o;
    for (int k = threadIdx.x; k < 512; k += 256) {
        float w = sinf((float)k * (float)(M_PI / 512.0));   // sqrt-hann
        float v;
        if (col == 16) {
            v = w * ((k & 1) ? -1.f : 1.f);
        } else {
            int mm = (bin * k) & 511;
            float th = (float)mm * (float)(2.0 * M_PI / 512.0);
            v = w * (isIm ? -sinf(th) : cosf(th));
        }
        __hip_bfloat16 h = __float2bfloat16(v);
        int ph = k >> 5, kq = (k >> 3) & 3, j = k & 7;
        size_t idx = (((size_t)ph * 32 + (col >> 4)) * 64
                      + kq * 16 + (col & 15)) * 8 + j;
        Bt[idx] = *reinterpret_cast<unsigned short*>(&h);
    }
}

// ---- MFMA DFT GEMM v13: B from L2 to registers, barrier-free K-loop -----
// grid (8 mchunk, 64 b, 2 s) = 1024 blocks, block 512 (8 waves, 1M x 8N).
// Block tile 64 rows x 512 cols; wave tile 64x64 (acc[4][4] = 64 acc regs).
// A: 64-frame bf16 window in LDS (33KB, XOR-swizzled), staged once.
// B: 512KB basis is L2-resident; per phase each wave loads 4 coalesced
//    fragments straight to registers, named ping-pong 1-phase prefetch.
// ONE barrier total (after A staging). No vmcnt(0) drains in the loop.
__global__ __launch_bounds__(512)
void dft_gemm(const float* __restrict__ sig,
              const float* __restrict__ intf,
              const unsigned short* __restrict__ Bt,
              _Float16* __restrict__ powo)
{
    __shared__ char As[SEGB];

    const int mchunk = blockIdx.x, b = blockIdx.y, s = blockIdx.z;
    const int tid = threadIdx.x, lane = tid & 63, wn = tid >> 6;  // 8 waves
    const int lq = lane >> 4, ll = lane & 15;
    const float* x = (s == 0 ? intf : sig) + (size_t)b * NSAMP;
    const int tbase = mchunk * 16384 - 256;

    // ---- A staging: contiguous segment, float4, bf16, addr-XOR swizzle ----
    {
        const int jlo = (tbase < 0) ? -tbase : 0;
        const int jhi = (tbase + SEG > NSAMP) ? (NSAMP - tbase) : SEG;
        for (int i = tid; i < SEG / 4; i += 512) {
            int j = i * 4;
            float f0, f1, f2, f3;
            if (j >= jlo && j + 4 <= jhi) {
                float4 v = *(const float4*)(x + tbase + j);
                f0 = v.x; f1 = v.y; f2 = v.z; f3 = v.w;
            } else {
                int p0 = tbase + j;
                int pp[4];
                #pragma unroll
                for (int e = 0; e < 4; ++e) {
                    int p = p0 + e;
                    if (p < 0) p = -p;
                    if (p >= NSAMP) p = 2 * NSAMP - 2 - p;
                    pp[e] = p;
                }
                f0 = x[pp[0]]; f1 = x[pp[1]]; f2 = x[pp[2]]; f3 = x[pp[3]];
            }
            unsigned short h[4];
            __hip_bfloat16 t0 = __float2bfloat16(f0); h[0] = *(unsigned short*)&t0;
            __hip_bfloat16 t1 = __float2bfloat16(f1); h[1] = *(unsigned short*)&t1;
            __hip_bfloat16 t2 = __float2bfloat16(f2); h[2] = *(unsigned short*)&t2;
            __hip_bfloat16 t3 = __float2bfloat16(f3); h[3] = *(unsigned short*)&t3;
            u64 pk = (u64)h[0] | ((u64)h[1] << 16) |
                     ((u64)h[2] << 32) | ((u64)h[3] << 48);
            int a = i * 8;
            a ^= ((a >> 9) & 7) << 4;
            *(u64*)(As + a) = pk;
        }
    }
    __syncthreads();    // the ONLY barrier: A ready; K-loop free-runs

    f32x4 acc[4][4];
    #pragma unroll
    for (int i = 0; i < 4; ++i)
        #pragma unroll
        for (int j = 0; j < 4; ++j) acc[i][j] = 0;

    // per-lane byte base into basis for this wave's 4 col-groups
    const char* bb = (const char*)Bt + (size_t)(wn * 4 * 64 + lane) * 16;

    bf16x8 curB[4], nxtB[4];
    #pragma unroll
    for (int nf = 0; nf < 4; ++nf)
        curB[nf] = *(const bf16x8*)(bb + nf * 1024);

    #pragma unroll 1
    for (int ph = 0; ph < 16; ++ph) {
        // A fragments for this phase (LDS, 2-way max conflict)
        bf16x8 af[4];
        #pragma unroll
        for (int mf = 0; mf < 4; ++mf) {
            int a = (mf * 16 + ll) * 512 + ph * 64 + lq * 16;
            a ^= ((a >> 9) & 7) << 4;
            af[mf] = *(const bf16x8*)(As + a);
        }
        // prefetch next phase's B fragments (L2 hit, hidden under MFMAs)
        if (ph < 15) {
            const char* bp = bb + (size_t)(ph + 1) * BPHB;
            #pragma unroll
            for (int nf = 0; nf < 4; ++nf)
                nxtB[nf] = *(const bf16x8*)(bp + nf * 1024);
        }
        __builtin_amdgcn_s_setprio(1);
        #pragma unroll
        for (int mf = 0; mf < 4; ++mf)
            #pragma unroll
            for (int nf = 0; nf < 4; ++nf)
                acc[mf][nf] = __builtin_amdgcn_mfma_f32_16x16x32_bf16(
                    af[mf], curB[nf], acc[mf][nf], 0, 0, 0);
        __builtin_amdgcn_s_setprio(0);
        #pragma unroll
        for (int nf = 0; nf < 4; ++nf) curB[nf] = nxtB[nf];
    }

    // ---- epilogue: power = re^2 + im^2, fp16 stores ----
    const size_t rowbase = ((size_t)(s * 64 + b)) * TFR;
    #pragma unroll
    for (int mf = 0; mf < 4; ++mf) {
        #pragma unroll
        for (int p = 0; p < 2; ++p) {
            f32x4 re = acc[mf][2 * p], im = acc[mf][2 * p + 1];
            int gbin = wn * 2 + p;
            int bin = gbin * 16 + ll;
            bool nyq = (gbin == 0) && (ll == 0);
            #pragma unroll
            for (int j = 0; j < 4; ++j) {
                int rl = mchunk * 64 + mf * 16 + lq * 4 + j;
                if (rl < TFR) {
                    float pr = re[j] * re[j];
                    float pi = im[j] * im[j];
                    _Float16* po = powo + (rowbase + rl) * FPOW;
                    po[bin] = (_Float16)(nyq ? pr : (pr + pi));
                    if (nyq) po[256] = (_Float16)pi;
                }
            }
        }
    }
}

// ---- warm-up: batched loads then fmaf chain (fp16 planes) ---------------
template<int W>
__device__ __forceinline__ float warm_sum(const _Float16* __restrict__ nrow,
                                          int ts, float alpha, float oma) {
    float q[W + 1];
    #pragma unroll
    for (int i = 0; i <= W; ++i) q[i] = (float)nrow[(size_t)(ts + i) * FPOW];
    float v = q[0];
    #pragma unroll
    for (int i = 1; i <= W; ++i) v = fmaf(alpha, v, oma * q[i]);
    return v;
}

// ---- chunked IIR scan + SPP + MSE, fp16 power planes --------------------
__global__ __launch_bounds__(256, 4)
void spp_loss_kernel(const _Float16* __restrict__ noiseP,
                     const _Float16* __restrict__ noisyP,
                     const float* __restrict__ est,
                     float* __restrict__ out,
                     float alpha)
{
    const double XI = 31.622776601683793;
    const float RATIO = (float)(1.0 + XI);
    const float COEF  = (float)(XI / (1.0 + XI));
    const float INVN  = (float)(1.0 / ((double)B_SZ * NF * TFR));

    int tid = blockIdx.x * blockDim.x + threadIdx.x;
    int f   = tid % NF;
    int rem = tid / NF;
    int c   = rem & (NCH - 1);
    int b   = rem >> 4;

    float local = 0.f;
    if (b < B_SZ) {
        const int t0   = c * CHUNKT;
        const int tend = min(TFR, t0 + CHUNKT);
        const _Float16* nrow = noiseP + (size_t)b * TFR * FPOW + f;
        const _Float16* yrow = noisyP + (size_t)b * TFR * FPOW + f;
        const float* erow = est + ((size_t)b * NF + f) * TFR;
        const float oma = 1.f - alpha;

        float v;
        if (t0 == 0)            v = (float)nrow[0];
        else if (t0 == CHUNKT)  v = warm_sum<CHUNKT>(nrow, 0, alpha, oma);
        else                    v = warm_sum<48>(nrow, t0 - 48, alpha, oma);

        {
            float np = (float)yrow[(size_t)t0 * FPOW];
            float e0 = erow[t0];
            float expo = -np / (v + EPS_F) * COEF;
            float spp  = 1.f / fmaf(RATIO, __expf(expo), 1.f);
            float d = e0 - spp;
            local = fmaf(d, d, local);
        }
        #pragma unroll
        for (int h = 0; h < 2; ++h) {
            float qn[16], qy[16], qe[16];
            #pragma unroll
            for (int i = 0; i < 16; ++i) {
                int t = min(t0 + h * 16 + i + 1, TFR - 1);
                qn[i] = (float)nrow[(size_t)t * FPOW];
                qy[i] = (float)yrow[(size_t)t * FPOW];
                qe[i] = erow[t];
            }
            #pragma unroll
            for (int i = 0; i < 16; ++i) {
                int t = t0 + h * 16 + i + 1;
                v = fmaf(alpha, v, oma * qn[i]);
                if (t < tend) {
                    float expo = -qy[i] / (v + EPS_F) * COEF;
                    float spp  = 1.f / fmaf(RATIO, __expf(expo), 1.f);
                    float d = qe[i] - spp;
                    local = fmaf(d, d, local);
                }
            }
        }
    }

    for (int off = 32; off > 0; off >>= 1)
        local += __shfl_down(local, off);
    __shared__ float wsum[4];
    if ((threadIdx.x & 63) == 0) wsum[threadIdx.x >> 6] = local;
    __syncthreads();
    if (threadIdx.x == 0) {
        float ssum = (wsum[0] + wsum[1]) + (wsum[2] + wsum[3]);
        atomicAdd(out, ssum * INVN);
    }
}

extern "C" void kernel_launch(void* const* d_in, const int* in_sizes, int n_in,
                              void* d_out, int out_size, void* d_ws, size_t ws_size,
                              hipStream_t stream) {
    const float* est  = (const float*)d_in[0];   // spp_estimate (B,1,F,T)
    const float* sig  = (const float*)d_in[1];   // input_sig    (B,1,N)
    const float* intf = (const float*)d_in[2];   // interference (B,1,N)

    unsigned short* Bt = (unsigned short*)d_ws;                 // 512 KB basis
    _Float16* powp = (_Float16*)((char*)d_ws + (size_t)512 * 1024);

    hipLaunchKernelGGL(build_basis, dim3(512), dim3(256), 0, stream, Bt);
    hipMemsetAsync(d_out, 0, sizeof(float), stream);

    dim3 gG(8, 64, 2);
    hipLaunchKernelGGL(dft_gemm, gG, dim3(512), 0, stream,
                       sig, intf, Bt, powp);

    const double alpha_d = exp(-((double)256) / (16000.0 * 0.072));
    const _Float16* noiseP = powp;                          // s=0: interference
    const _Float16* noisyP = powp + (size_t)NFR * FPOW;     // s=1: input_sig
    dim3 gB((B_SZ * NCH * NF + 255) / 256);
    hipLaunchKernelGGL(spp_loss_kernel, gB, dim3(256), 0, stream,
                       noiseP, noisyP, est, (float*)d_out, (float)alpha_d);
}